// Round 9
// baseline (228.368 us; speedup 1.0000x reference)
//
#include <hip/hip_runtime.h>

// GraphAugmentation fused kernel, MI355X — R9: LDS row-staging stencil.
//
// Algebra (unchanged):
//  * softmax over 8 identical affinities == 1/8 -> Q/K/attn dead.
//  * u = [xc ; xavg] (K=32), xavg = mean of 8 rolls of x.
//  * agg    = [0|mw] @ u + mb
//  * hidden = relu(W1' @ u + b1'), W1' = [g1w_x | g1w_a@mw] (rows permuted
//             so hidden MFMA D-regs ARE the gate B-fragment — R7-proven)
//  * gate   = sigmoid(g2w @ hidden + g2b);  out = agg * gate
//
// R9 vs R5-R8 (~90us, latency-bound on per-thread global gathers):
//  * per channel, stage 7 source rows (center + 6 tap rows, echo halo +-4)
//    into LDS via global_load_lds width=16 (slot s -> lds byte 16s is
//    exactly base+16*lane; every 16B chunk is wrap-free since 512%4==0).
//    Double-buffered: stage(c+1) in flight under taps(c); 1 sync/channel.
//  * taps = ds_read2_b32 with compile-time offsets (vaddr=4t per row),
//    both pixels (t, t+128) in one instr; zero wrap logic, zero addr VALU.
//  * rows region (2 x 8KB) reused as u staging (16KB union) after gather
//    -> LDS 18.6KB -> 8 blocks/CU = 16 waves/CU.
//
// Row buffer layout (per buf, 2048 dwords): rows j=0..6 at j*264, halo map
// lds[j][i] = x[(row+d_j)&511][(cb-4+i)&511], d = {4,3,2,0,-2,-3,-4}.
// Tap (j,dx) read idx = j*264 + (4-dx) + t  (and +128 for pixel 2):
//   (0,-4):+8  (0,-1):+5  (0,2):+2  (1,4):264  (2,-3):528+7
//   (4,3):1056+1  (5,-2):1320+6  (6,4):1584  center(3,0):792+4

#define HW 262144   // 512*512
#define WD 512

typedef _Float16 half8 __attribute__((ext_vector_type(8)));
typedef float    f32x4 __attribute__((ext_vector_type(4)));

#define MFMA16(A, B, C) __builtin_amdgcn_mfma_f32_16x16x32_f16((A), (B), (C), 0, 0, 0)

__device__ __forceinline__ void gload_lds16(const float* g, char* l) {
  __builtin_amdgcn_global_load_lds(
      (const __attribute__((address_space(1))) void*)g,
      (__attribute__((address_space(3))) void*)l, 16, 0, 0);
}

__global__ __launch_bounds__(128) void ga_main(
    const float* __restrict__ x,
    const float* __restrict__ mw,  const float* __restrict__ mb,
    const float* __restrict__ g1w, const float* __restrict__ g1b,
    const float* __restrict__ g2w, const float* __restrict__ g2b,
    float* __restrict__ out)
{
  __shared__ __align__(16) char sh_raw[16384];  // rows[2][2048 f32] U u[4][256][8 f16]
  __shared__ float w1a[512];                    // W1' columns k>=16
  __shared__ float b1s[32];                     // b1' = g1b + g1w_a @ mb

  const int t    = threadIdx.x;                 // 0..127
  const int wv   = t >> 6, lane = t & 63;
  const int q    = lane >> 4, m = lane & 15;

  // ---- block-cooperative prep: W1'a[j][c] and b1'[j] into LDS ----
  for (int idx = t; idx < 512; idx += 128) {
    const int j = idx >> 4, c = idx & 15;
    float s = 0.f;
#pragma unroll
    for (int t2 = 0; t2 < 16; ++t2)
      s += g1w[j * 32 + 16 + t2] * mw[t2 * 16 + c];
    w1a[idx] = s;
  }
  if (t < 32) {
    float s = g1b[t];
#pragma unroll
    for (int t2 = 0; t2 < 16; ++t2)
      s += g1w[t * 32 + 16 + t2] * mb[t2];
    b1s[t] = s;
  }

  // ---- XCD-aware bijective swizzle: 4096 wgs, chunk 512 ----
  const int swz = ((blockIdx.x & 7) << 9) | (blockIdx.x >> 3);
  const int b   = swz >> 10;
  const int rem = swz & 1023;
  const int row = rem >> 1;
  const int cb  = (rem & 1) << 8;        // block covers cols [cb, cb+255]

  const float* xb = x + b * 16 * HW;

  // ---- per-slot global element offsets (channel-independent) ----
  // slot s = t + 128*it, s in [0,512): row j = s/66, chunk k = s%66.
  // slots >= 462 are harmless pad loads (still in-bounds of the image).
  unsigned goff[4];
#pragma unroll
  for (int it = 0; it < 4; ++it) {
    const int s = t + 128 * it;
    const int j = s / 66;
    const int k = s - 66 * j;
    const int d = (j < 3) ? (4 - j) : ((j == 3) ? 0 : (2 - j));
    const int srow = (row + d) & 511;
    goff[it] = srow * WD + ((cb - 4 + 4 * k) & 511);
  }

  // ---- stage channel 0 into buf 0 ----
#pragma unroll
  for (int it = 0; it < 4; ++it)
    gload_lds16(xb + goff[it], sh_raw + 16 * (t + 128 * it));
  __syncthreads();

  // ---- gather phase: per channel, taps from LDS; prefetch next channel ----
  float xc0[16], xc1[16], xa0[16], xa1[16];
  const float* rows = (const float*)sh_raw;

#pragma unroll
  for (int c = 0; c < 16; ++c) {
    if (c < 15) {
      const float* xpn = xb + (c + 1) * HW;
      char* dst = sh_raw + ((c + 1) & 1) * 8192;
#pragma unroll
      for (int it = 0; it < 4; ++it)
        gload_lds16(xpn + goff[it], dst + 16 * (t + 128 * it));
    }
    const float* rb = rows + (c & 1) * 2048;
    xc0[c] = rb[792 + 4 + t];
    xc1[c] = rb[792 + 132 + t];
    float s0, s1;
    s0  = rb[   8 + t];   s1  = rb[ 136 + t];   // (dy-4,dx-4)
    s0 += rb[   5 + t];   s1 += rb[ 133 + t];   // (dy-4,dx-1)
    s0 += rb[   2 + t];   s1 += rb[ 130 + t];   // (dy-4,dx 2)
    s0 += rb[ 264 + t];   s1 += rb[ 392 + t];   // (dy-3,dx 4)
    s0 += rb[ 535 + t];   s1 += rb[ 663 + t];   // (dy-2,dx-3): 528+7
    s0 += rb[1057 + t];   s1 += rb[1185 + t];   // (dy 2,dx 3): 1056+1
    s0 += rb[1326 + t];   s1 += rb[1454 + t];   // (dy 3,dx-2): 1320+6
    s0 += rb[1584 + t];   s1 += rb[1712 + t];   // (dy 4,dx 4)
    xa0[c] = s0 * 0.125f;
    xa1[c] = s1 * 0.125f;
    __syncthreads();
  }

  // ---- rows dead for all waves: reuse region as u staging ----
  __syncthreads();
  _Float16* up = (_Float16*)sh_raw;   // u[cq][px][8]: half idx = cq*2048 + px*8
  {
    half8 h;
#pragma unroll
    for (int e = 0; e < 8; ++e) h[e] = (_Float16)xc0[e];
    *(half8*)(up + 0 * 2048 + t * 8) = h;
#pragma unroll
    for (int e = 0; e < 8; ++e) h[e] = (_Float16)xc0[8 + e];
    *(half8*)(up + 1 * 2048 + t * 8) = h;
#pragma unroll
    for (int e = 0; e < 8; ++e) h[e] = (_Float16)xa0[e];
    *(half8*)(up + 2 * 2048 + t * 8) = h;
#pragma unroll
    for (int e = 0; e < 8; ++e) h[e] = (_Float16)xa0[8 + e];
    *(half8*)(up + 3 * 2048 + t * 8) = h;
#pragma unroll
    for (int e = 0; e < 8; ++e) h[e] = (_Float16)xc1[e];
    *(half8*)(up + 0 * 2048 + (t + 128) * 8) = h;
#pragma unroll
    for (int e = 0; e < 8; ++e) h[e] = (_Float16)xc1[8 + e];
    *(half8*)(up + 1 * 2048 + (t + 128) * 8) = h;
#pragma unroll
    for (int e = 0; e < 8; ++e) h[e] = (_Float16)xa1[e];
    *(half8*)(up + 2 * 2048 + (t + 128) * 8) = h;
#pragma unroll
    for (int e = 0; e < 8; ++e) h[e] = (_Float16)xa1[8 + e];
    *(half8*)(up + 3 * 2048 + (t + 128) * 8) = h;
  }

  // ---- per-lane weight A-fragments (fp16 hi+lo); hidden rows permuted ----
  const int j0 = 8 * (m >> 2) + (m & 3);
  const int j1 = j0 + 4;
  half8 aAg_h, aAg_l, aH0_h, aH0_l, aH1_h, aH1_l, aG2_h, aG2_l;
#pragma unroll
  for (int e = 0; e < 8; ++e) {
    const int kk = 8 * q + e;
    float v0 = 0.f;
    if (kk >= 16) v0 = mw[m * 16 + (kk - 16)];      // Abar = [0 | mw]
    _Float16 h = (_Float16)v0;
    aAg_h[e] = h; aAg_l[e] = (_Float16)(v0 - (float)h);

    float v1, v2;
    if (kk < 16) { v1 = g1w[j0 * 32 + kk];        v2 = g1w[j1 * 32 + kk]; }
    else         { v1 = w1a[j0 * 16 + (kk - 16)]; v2 = w1a[j1 * 16 + (kk - 16)]; }
    h = (_Float16)v1; aH0_h[e] = h; aH0_l[e] = (_Float16)(v1 - (float)h);
    h = (_Float16)v2; aH1_h[e] = h; aH1_l[e] = (_Float16)(v2 - (float)h);

    const float v3 = g2w[m * 32 + kk];
    h = (_Float16)v3; aG2_h[e] = h; aG2_l[e] = (_Float16)(v3 - (float)h);
  }
  f32x4 bias0, bias1, bias2, bias3;
#pragma unroll
  for (int rg = 0; rg < 4; ++rg) {
    bias0[rg] = mb[4 * q + rg];
    bias1[rg] = b1s[8 * q + rg];        // acc_h0 reg rg = h-ch 8q+rg
    bias2[rg] = b1s[8 * q + 4 + rg];    // acc_h1 reg rg = h-ch 8q+4+rg
    bias3[rg] = g2b[4 * q + rg];
  }

  // ---- MFMA phase: wave-private groups (own staged pixels) ----
  // wave 0: px 0..63 & 128..191 -> groups {0..3, 8..11}; wave 1: the rest.
  float* ob = out + b * 16 * HW + row * WD + cb;
  const f32x4 z = {0.f, 0.f, 0.f, 0.f};

#pragma unroll
  for (int gi = 0; gi < 8; ++gi) {
    const int g = wv * 4 + (gi & 3) + (gi >> 2) * 8;
    const half8 bf = *(const half8*)(up + q * 2048 + (16 * g + m) * 8);

    f32x4 acc_a  = MFMA16(aAg_l, bf, z);
    acc_a        = MFMA16(aAg_h, bf, acc_a);
    f32x4 acc_h0 = MFMA16(aH0_l, bf, z);
    acc_h0       = MFMA16(aH0_h, bf, acc_h0);
    f32x4 acc_h1 = MFMA16(aH1_l, bf, z);
    acc_h1       = MFMA16(aH1_h, bf, acc_h1);

    // relu + fp16 pack: registers ARE the gate B-fragment (row-permuted W1')
    half8 gB;
#pragma unroll
    for (int rg = 0; rg < 4; ++rg) {
      gB[rg]     = (_Float16)fmaxf(acc_h0[rg] + bias1[rg], 0.f);
      gB[4 + rg] = (_Float16)fmaxf(acc_h1[rg] + bias2[rg], 0.f);
    }

    f32x4 acc_g = MFMA16(aG2_l, gB, z);
    acc_g       = MFMA16(aG2_h, gB, acc_g);

    // epilogue: out = (agg+mb) * sigmoid(gate_pre + g2b)
#pragma unroll
    for (int rg = 0; rg < 4; ++rg) {
      const float ag = acc_a[rg] + bias0[rg];
      const float gp = acc_g[rg] + bias3[rg];
      const float gt = __builtin_amdgcn_rcpf(1.f + __expf(-gp));
      ob[(4 * q + rg) * HW + 16 * g + m] = ag * gt;
    }
  }
}

extern "C" void kernel_launch(void* const* d_in, const int* in_sizes, int n_in,
                              void* d_out, int out_size, void* d_ws, size_t ws_size,
                              hipStream_t stream) {
  // setup_inputs() order:
  // 0:x 1:qw 2:qb 3:kw 4:kb 5:mw 6:mb 7:scaling 8:g1w 9:g1b 10:g2w 11:g2b
  const float* x   = (const float*)d_in[0];
  const float* mw  = (const float*)d_in[5];
  const float* mb  = (const float*)d_in[6];
  const float* g1w = (const float*)d_in[8];
  const float* g1b = (const float*)d_in[9];
  const float* g2w = (const float*)d_in[10];
  const float* g2b = (const float*)d_in[11];
  float* out = (float*)d_out;

  // 4096 wgs x 128 thr; block = half an image row (256 px, 2 px/thread).
  ga_main<<<4096, 128, 0, stream>>>(x, mw, mb, g1w, g1b, g2w, g2b, out);
}